// Round 10
// baseline (206.791 us; speedup 1.0000x reference)
//
#include <hip/hip_runtime.h>
#include <hip/hip_bf16.h>

typedef unsigned short u16;
typedef unsigned int u32;
typedef float f32x4 __attribute__((ext_vector_type(4)));
typedef short bf16x8 __attribute__((ext_vector_type(8)));

// ---- constants (B=2, S=2048, E=1024, H=16, D=64) ----
#define BB 2
#define SS 2048
#define EE 1024
#define HH 16
#define DD 64
// q pre-scale: 1/sqrt(D) * log2(e) — scores land directly in exp2 domain.
#define QSCALE 0.18033688011f

__device__ __forceinline__ u16 f2bf(float f) {
    union { u32 i; float f; } x; x.f = f;
    return (u16)((x.i + 0x7FFFu + ((x.i >> 16) & 1u)) >> 16);
}
__device__ __forceinline__ u32 pkbf(float a, float b) {
    __hip_bfloat162 h = __float22bfloat162_rn(make_float2(a, b));
    union { __hip_bfloat162 h; u32 u; } c; c.h = h; return c.u;
}

#define MFMA16(a, b, c) __builtin_amdgcn_mfma_f32_16x16x32_bf16((a), (b), (c), 0, 0, 0)

// async global->LDS DMA, 16B per lane; LDS dest = wave-uniform base + lane*16
__device__ __forceinline__ void gld16(const u16* g, u16* l) {
    __builtin_amdgcn_global_load_lds(
        (const __attribute__((address_space(1))) void*)g,
        (__attribute__((address_space(3))) void*)l,
        16, 0, 0);
}

// ============================================================
// GEMM1 v6: qkv = x*W_attn^T + b_attn — FUSED fp32->bf16 convert.
// convert_all is eliminated: A (x fp32) and B (W_attn fp32) are staged
// via reg-path (2x float4 load -> pkbf pack -> ds_write_b128) into the
// SAME swizzled LDS layout the gld16 path used (csw is an elem offset,
// identical for fp32 source addressing). Rounding identical to the old
// convert kernel (__float22bfloat162_rn) -> bit-identical numerics.
// Saves the convert dispatch (~10 us) + one inter-dispatch gap.
// VGPR: reg-staging adds ~32 live regs -> __launch_bounds__(512,4)
// (128-VGPR budget, no spill risk; 2 blocks/CU, 32 KB LDS, accepts the
// 768=512+256 tail that (512,6) removed — tail was only ~2 us).
// grid (24, 32): XCD = x%8 — W n-slices L2-resident.
// ============================================================
__global__ __launch_bounds__(512, 4) void gemm_qkv(
    const float* __restrict__ A, const float* __restrict__ B, const float* __restrict__ bias,
    u16* __restrict__ Qo, u16* __restrict__ Ko, u16* __restrict__ Vto)
{
    __shared__ __align__(16) u16 SMEM[16384];      // As[128*64] | Bs[128*64]; T aliases
    u16* As = SMEM;
    u16* Bs = SMEM + 8192;
    const int n0 = blockIdx.x * 128, m0 = blockIdx.y * 128;
    const int tid = threadIdx.x;
    const int wave = tid >> 6, lane = tid & 63;
    const int l16 = lane & 15, quad = lane >> 4;
    const int wm = wave >> 2, wn = wave & 3;       // 2x4 wave grid
    const int ldr = lane >> 3;
    const int csw = ((lane & 7) ^ ldr) * 8;        // swizzled k-chunk (elems)

    f32x4 acc[4][2];
#pragma unroll
    for (int i = 0; i < 4; ++i)
#pragma unroll
        for (int j = 0; j < 2; ++j) acc[i][j] = f32x4{0.f, 0.f, 0.f, 0.f};

    const int aorb = wave >> 2;                    // 0: stage A, 1: stage B
    const float* stgsrc = aorb ? B : A;
    const int stgbase = aorb ? n0 : m0;
    u16* stgbuf = aorb ? Bs : As;

    for (int k0 = 0; k0 < 1024; k0 += 64) {
        __syncthreads();
#pragma unroll
        for (int t = 0; t < 4; ++t) {
            const int c = (wave & 3) * 4 + t;      // 0..15
            const int row = c * 8 + ldr;
            const float* sp = stgsrc + (size_t)(stgbase + row) * 1024 + k0 + csw;
            float4 va = *(const float4*)sp;
            float4 vb = *(const float4*)(sp + 4);
            uint4 w;
            w.x = pkbf(va.x, va.y); w.y = pkbf(va.z, va.w);
            w.z = pkbf(vb.x, vb.y); w.w = pkbf(vb.z, vb.w);
            *(uint4*)&stgbuf[c * 512 + lane * 8] = w;
        }
        __syncthreads();
#pragma unroll
        for (int ks = 0; ks < 2; ++ks) {
            bf16x8 af[4], bf[2];
#pragma unroll
            for (int i = 0; i < 4; ++i)
                af[i] = *(const bf16x8*)&As[(wm * 64 + i * 16 + l16) * 64 +
                                            ((ks * 4 + quad) ^ (l16 & 7)) * 8];
#pragma unroll
            for (int j = 0; j < 2; ++j)
                bf[j] = *(const bf16x8*)&Bs[(wn * 32 + j * 16 + l16) * 64 +
                                            ((ks * 4 + quad) ^ (l16 & 7)) * 8];
#pragma unroll
            for (int i = 0; i < 4; ++i)
#pragma unroll
                for (int j = 0; j < 2; ++j)
                    acc[i][j] = MFMA16(af[i], bf[j], acc[i][j]);
        }
    }

    const int part = blockIdx.x >> 3;              // 0=q,1=k,2=v
    const int hbase = (blockIdx.x & 7) << 1;
    if (part != 2) {
        const int h = hbase + (wn >> 1);           // uniform per wave
#pragma unroll
        for (int j = 0; j < 2; ++j) {
            const int f = n0 + wn * 32 + j * 16 + l16;
            const int d = f & 63;
            const float bj = bias[f];
#pragma unroll
            for (int i = 0; i < 4; ++i) {
#pragma unroll
                for (int r = 0; r < 4; ++r) {
                    const int m = m0 + wm * 64 + i * 16 + quad * 4 + r;
                    const int b = m >> 11, s = m & 2047;
                    const float val = acc[i][j][r] + bj;
                    if (part == 0)
                        Qo[(((size_t)(b * HH + h)) * SS + s) * DD + d] = f2bf(val * QSCALE);
                    else
                        Ko[(((size_t)(b * HH + h)) * SS + s) * DD + d] = f2bf(val);
                }
            }
        }
    } else {
        // V: transpose C-tile (128 m x 128 f) through T (aliases SMEM),
        // two m-half passes, coalesced 8B stores to [B,H,D,S].
        u16* T = SMEM;                             // 128 x 72 = 18432 B
#pragma unroll
        for (int wmr = 0; wmr < 2; ++wmr) {
            __syncthreads();
            if (wm == wmr) {
#pragma unroll
                for (int j = 0; j < 2; ++j) {
                    const float bj = bias[n0 + wn * 32 + j * 16 + l16];
#pragma unroll
                    for (int i = 0; i < 4; ++i) {
                        uint2 pw;
                        pw.x = pkbf(acc[i][j][0] + bj, acc[i][j][1] + bj);
                        pw.y = pkbf(acc[i][j][2] + bj, acc[i][j][3] + bj);
                        *(uint2*)&T[(wn * 32 + j * 16 + l16) * 72 + i * 16 + quad * 4] = pw;
                    }
                }
            }
            __syncthreads();
            const int frow = tid >> 2;             // 0..127 (f_local)
            const int qtr = tid & 3;
            const int h = hbase + (frow >> 6);
            const int d = frow & 63;
            const int mg = m0 + wmr * 64;
            const int b = mg >> 11, sbase = mg & 2047;
            u16* dstrow = Vto + (((size_t)(b * HH + h)) * DD + d) * SS + sbase;
#pragma unroll
            for (int l = 0; l < 4; ++l) {
                const int mo = qtr * 16 + l * 4;
                *(uint2*)(dstrow + mo) = *(const uint2*)&T[frow * 72 + mo];
            }
        }
    }
}

// ============================================================
// GEMM2 v6: out = o*W_proj^T + b_proj (fp32) — 64x128 tile, 8 waves,
// double-buffered staging, grid (64, 8) (XCD = m%8, R6 win).
// FUSED W_proj convert: A chunks (attn output, bf16) keep gld16 DMA;
// B chunks (W_proj fp32) go reg-path load->pkbf->ds_write into the
// same swizzled layout. 512 blocks = 2/CU exact.
// ============================================================
__global__ __launch_bounds__(512, 4) void gemm_proj(
    const u16* __restrict__ A, const float* __restrict__ B, const float* __restrict__ bias,
    float* __restrict__ out)
{
    __shared__ __align__(16) u16 SMEM[2][12288];   // [buf]{As[64*64] | Bs[128*64]}
    const int n0 = blockIdx.y * 128, m0 = blockIdx.x * 64;
    const int tid = threadIdx.x;
    const int wave = tid >> 6, lane = tid & 63;
    const int l16 = lane & 15, quad = lane >> 4;
    const int wm = wave >> 2, wn = wave & 3;       // 2x4 wave grid
    const int ldr = lane >> 3;
    const int csw = ((lane & 7) ^ ldr) * 8;

    f32x4 acc[2][2];
#pragma unroll
    for (int i = 0; i < 2; ++i)
#pragma unroll
        for (int j = 0; j < 2; ++j) acc[i][j] = f32x4{0.f, 0.f, 0.f, 0.f};

    auto stage = [&](int k0, int buf) {
#pragma unroll
        for (int t = 0; t < 3; ++t) {
            const int c = wave * 3 + t;            // 0..23: A chunks 0-7, B 8-23
            if (c < 8) {
                const int row = c * 8 + ldr;
                gld16(A + (size_t)(m0 + row) * 1024 + k0 + csw,
                      &SMEM[buf][c * 512 + lane * 8]);
            } else {
                const int c2 = c - 8;
                const int row = c2 * 8 + ldr;
                const float* sp = B + (size_t)(n0 + row) * 1024 + k0 + csw;
                float4 va = *(const float4*)sp;
                float4 vb = *(const float4*)(sp + 4);
                uint4 w;
                w.x = pkbf(va.x, va.y); w.y = pkbf(va.z, va.w);
                w.z = pkbf(vb.x, vb.y); w.w = pkbf(vb.z, vb.w);
                *(uint4*)&SMEM[buf][4096 + c2 * 512 + lane * 8] = w;
            }
        }
    };

    stage(0, 0);                                   // prologue
    for (int k0 = 0; k0 < 1024; k0 += 64) {
        const int cur = (k0 >> 6) & 1;
        __syncthreads();
        if (k0 + 64 < 1024) stage(k0 + 64, cur ^ 1);
        const u16* As = SMEM[cur];
        const u16* Bs = SMEM[cur] + 4096;
#pragma unroll
        for (int ks = 0; ks < 2; ++ks) {
            bf16x8 af[2], bf[2];
#pragma unroll
            for (int i = 0; i < 2; ++i)
                af[i] = *(const bf16x8*)&As[(wm * 32 + i * 16 + l16) * 64 +
                                            ((ks * 4 + quad) ^ (l16 & 7)) * 8];
#pragma unroll
            for (int j = 0; j < 2; ++j)
                bf[j] = *(const bf16x8*)&Bs[(wn * 32 + j * 16 + l16) * 64 +
                                            ((ks * 4 + quad) ^ (l16 & 7)) * 8];
#pragma unroll
            for (int i = 0; i < 2; ++i)
#pragma unroll
                for (int j = 0; j < 2; ++j)
                    acc[i][j] = MFMA16(af[i], bf[j], acc[i][j]);
        }
    }
#pragma unroll
    for (int j = 0; j < 2; ++j) {
        const int f = n0 + wn * 32 + j * 16 + l16;
        const float bj = bias[f];
#pragma unroll
        for (int i = 0; i < 2; ++i) {
#pragma unroll
            for (int r = 0; r < 4; ++r) {
                const int m = m0 + wm * 32 + i * 16 + quad * 4 + r;
                out[(size_t)m * EE + f] = acc[i][j][r] + bj;
            }
        }
    }
}

// ============================================================
// MFMA flash attention v8: best-measured attn (~38 µs), unchanged.
// Constraint set (R5-R7): >=2 blocks/CU AND balanced per-block work
// AND K/V reuse can't all hold at 256-thr blocks; v8 is the local opt.
// 512 blocks x 256 thr (2/CU), dbuf K/V pairs, two k-tiles per barrier,
// pair-balanced q-tiles (33 phases/block), setprio.
// grid (32,16): x = bh -> XCD = bh % 8 (L2 locality, round 2 win).
// ============================================================
__global__ __launch_bounds__(256, 2) void attn(
    const u16* __restrict__ Q, const u16* __restrict__ K, const u16* __restrict__ VT,
    u16* __restrict__ O)
{
    const int p = blockIdx.y;              // 0..15  (pair index)
    const int bh = blockIdx.x;             // 0..31  -> XCD = bh % 8
    const int tid = threadIdx.x;
    const int wave = tid >> 6, lane = tid & 63;
    const int l16 = lane & 15, quad = lane >> 4;
    const int ldr = lane >> 3;
    const int csw = ((lane & 7) ^ ldr) * 8;
    __shared__ __align__(16) u16 Ks[2][2][64 * 64];   // [buf][sub]
    __shared__ __align__(16) u16 Vts[2][2][64 * 64];
    __shared__ __align__(16) u16 Ps[64 * 72];

    const u16* qptr = Q + (size_t)bh * SS * DD;
    const u16* kptr = K + (size_t)bh * SS * DD;
    const u16* vtptr = VT + (size_t)bh * DD * SS;
    const int b = bh >> 4, h = bh & 15;

    // stage k-tile `t` (and matching V^T columns) into [buf][sub]
    auto stage = [&](int t, int buf, int sub) {
#pragma unroll
        for (int c = 0; c < 2; ++c) {
            const int a0 = wave * 2 + c;
            const int row = a0 * 8 + ldr;
            gld16(kptr + (size_t)(t * 64 + row) * DD + csw,
                  &Ks[buf][sub][a0 * 512 + lane * 8]);
            gld16(vtptr + (size_t)row * SS + t * 64 + csw,
                  &Vts[buf][sub][a0 * 512 + lane * 8]);
        }
    };

    for (int half = 0; half < 2; ++half) {
        const int qb = half ? p : 31 - p;          // long tile first
        const int qrow = qb * 64 + wave * 16 + l16;   // this lane's query
        bf16x8 bq[2];
#pragma unroll
        for (int ks = 0; ks < 2; ++ks)
            bq[ks] = *(const bf16x8*)(qptr + (size_t)qrow * DD + ks * 32 + quad * 8);

        float lp = 0.f;                    // per-lane partial l
        f32x4 o_acc[4];
#pragma unroll
        for (int j = 0; j < 4; ++j) o_acc[j] = f32x4{0.f, 0.f, 0.f, 0.f};

        // per-subtile compute: QK^T -> masked exp2 -> P -> O += V^T P^T
        auto tile_compute = [&](const u16* Kb, const u16* Vb, int t) {
            f32x4 s[4];
#pragma unroll
            for (int j = 0; j < 4; ++j) s[j] = f32x4{0.f, 0.f, 0.f, 0.f};
            __builtin_amdgcn_s_setprio(1);
#pragma unroll
            for (int ks = 0; ks < 2; ++ks) {
#pragma unroll
                for (int j = 0; j < 4; ++j) {
                    bf16x8 ak = *(const bf16x8*)&Kb[(j * 16 + l16) * 64 +
                                                    ((ks * 4 + quad) ^ (l16 & 7)) * 8];
                    s[j] = MFMA16(ak, bq[ks], s[j]);
                }
            }
            __builtin_amdgcn_s_setprio(0);
            if (t == qb) {                 // mask only on the diagonal tile
#pragma unroll
                for (int j = 0; j < 4; ++j)
#pragma unroll
                    for (int r = 0; r < 4; ++r) {
                        const int key = t * 64 + j * 16 + quad * 4 + r;
                        if (key > qrow) s[j][r] = -INFINITY;   // exp2 -> 0
                    }
            }
#pragma unroll
            for (int j = 0; j < 4; ++j) {
                const float p0 = __builtin_amdgcn_exp2f(s[j][0]);
                const float p1 = __builtin_amdgcn_exp2f(s[j][1]);
                const float p2 = __builtin_amdgcn_exp2f(s[j][2]);
                const float p3 = __builtin_amdgcn_exp2f(s[j][3]);
                lp += (p0 + p1) + (p2 + p3);
                uint2 pw; pw.x = pkbf(p0, p1); pw.y = pkbf(p2, p3);
                *(uint2*)&Ps[(wave * 16 + l16) * 72 + j * 16 + quad * 4] = pw;
            }
            // O^T += V^T·P^T (Ps wave-private: lgkm ordering suffices)
            __builtin_amdgcn_s_setprio(1);
#pragma unroll
            for (int ks = 0; ks < 2; ++ks) {
                bf16x8 bp = *(const bf16x8*)&Ps[(wave * 16 + l16) * 72 + ks * 32 + quad * 8];
#pragma unroll
                for (int j = 0; j < 4; ++j) {
                    bf16x8 av = *(const bf16x8*)&Vb[(j * 16 + l16) * 64 +
                                                    ((ks * 4 + quad) ^ (l16 & 7)) * 8];
                    o_acc[j] = MFMA16(av, bp, o_acc[j]);
                }
            }
            __builtin_amdgcn_s_setprio(0);
        };

        // protect buf0 from the previous half's in-flight readers
        __syncthreads();
        // prologue: stage tile pair {0, min(1,qb)} into buf 0
        stage(0, 0, 0);
        stage(qb < 1 ? qb : 1, 0, 1);

        for (int kb = 0; kb <= qb; kb += 2) {
            const int cur = (kb >> 1) & 1;
            // vmcnt(0)+barrier (compiler-emitted): buf[cur] pair ready,
            // buf[cur^1] has no readers left.
            __syncthreads();
            if (kb + 2 <= qb) {            // prefetch next pair into buf^1
                stage(kb + 2, cur ^ 1, 0);
                const int t3 = kb + 3 > qb ? qb : kb + 3;   // clamp (no OOB)
                stage(t3, cur ^ 1, 1);
            }
            tile_compute(Ks[cur][0], Vts[cur][0], kb);
            if (kb + 1 <= qb)
                tile_compute(Ks[cur][1], Vts[cur][1], kb + 1);
        }

        // epilogue: quad-reduce l once, normalize, store (lane owns query qrow)
        float l = lp;
        l += __shfl_xor(l, 16);
        l += __shfl_xor(l, 32);
        const float inv = 1.0f / l;
#pragma unroll
        for (int j = 0; j < 4; ++j) {
            uint2 o4;
            o4.x = pkbf(o_acc[j][0] * inv, o_acc[j][1] * inv);
            o4.y = pkbf(o_acc[j][2] * inv, o_acc[j][3] * inv);
            *(uint2*)&O[((size_t)(b * SS + qrow)) * EE + h * DD + j * 16 + quad * 4] = o4;
        }
    }
}

extern "C" void kernel_launch(void* const* d_in, const int* in_sizes, int n_in,
                              void* d_out, int out_size, void* d_ws, size_t ws_size,
                              hipStream_t stream) {
    const float* x      = (const float*)d_in[0];  // [B,S,E] fp32
    const float* W_attn = (const float*)d_in[1];  // [3E,E] fp32
    const float* b_attn = (const float*)d_in[2];  // [3E] fp32
    const float* W_proj = (const float*)d_in[3];  // [E,E] fp32
    const float* b_proj = (const float*)d_in[4];  // [E] fp32
    float* out = (float*)d_out;                   // fp32 [B,S,E]

    // ws layout (u16 elems): ow 4.19M | q 4.19M | k 4.19M | vt 4.19M
    u16* ow  = (u16*)d_ws;                        // attn output [B,S,E] bf16
    u16* qw  = ow + (size_t)BB * SS * EE;
    u16* kw  = qw + (size_t)BB * HH * SS * DD;
    u16* vtw = kw + (size_t)BB * HH * SS * DD;

    gemm_qkv<<<dim3(24, 32), 512, 0, stream>>>(x, W_attn, b_attn, qw, kw, vtw);
    attn<<<dim3(32, 16), 256, 0, stream>>>(qw, kw, vtw, ow);
    gemm_proj<<<dim3(64, 8), 512, 0, stream>>>(ow, W_proj, b_proj, out);
}

// Round 11
// 177.683 us; speedup vs baseline: 1.1638x; 1.1638x over previous
//
#include <hip/hip_runtime.h>
#include <hip/hip_bf16.h>

typedef unsigned short u16;
typedef unsigned int u32;
typedef float f32x4 __attribute__((ext_vector_type(4)));
typedef short bf16x8 __attribute__((ext_vector_type(8)));

// ---- constants (B=2, S=2048, E=1024, H=16, D=64) ----
#define BB 2
#define SS 2048
#define EE 1024
#define HH 16
#define DD 64
// q pre-scale: 1/sqrt(D) * log2(e) — scores land directly in exp2 domain.
#define QSCALE 0.18033688011f

__device__ __forceinline__ u16 f2bf(float f) {
    union { u32 i; float f; } x; x.f = f;
    return (u16)((x.i + 0x7FFFu + ((x.i >> 16) & 1u)) >> 16);
}
__device__ __forceinline__ u32 pkbf(float a, float b) {
    __hip_bfloat162 h = __float22bfloat162_rn(make_float2(a, b));
    union { __hip_bfloat162 h; u32 u; } c; c.h = h; return c.u;
}

#define MFMA16(a, b, c) __builtin_amdgcn_mfma_f32_16x16x32_bf16((a), (b), (c), 0, 0, 0)

// async global->LDS DMA, 16B per lane; LDS dest = wave-uniform base + lane*16
__device__ __forceinline__ void gld16(const u16* g, u16* l) {
    __builtin_amdgcn_global_load_lds(
        (const __attribute__((address_space(1))) void*)g,
        (__attribute__((address_space(3))) void*)l,
        16, 0, 0);
}

// ============================================================
// fused fp32 -> bf16 convert of x | W_attn | W_proj into contiguous ws.
// R10 lesson: this dispatch is LOAD-BEARING — it deduplicates the fp32
// read (x read once, not once per n-block) and keeps GEMM staging on
// the async gld16 path. Fusing it into the GEMMs cost +36 us (R10).
// ============================================================
__global__ __launch_bounds__(256) void convert_all(
    const float* __restrict__ x, const float* __restrict__ wa,
    const float* __restrict__ wp, u16* __restrict__ dst)
{
    const size_t n0 = (size_t)4096 * 1024;
    const size_t n1 = n0 + (size_t)3072 * 1024;
    size_t i = ((size_t)blockIdx.x * 256 + threadIdx.x) * 4;
    const float* s;
    size_t off;
    if (i < n0)      { s = x;  off = 0;  }
    else if (i < n1) { s = wa; off = n0; }
    else             { s = wp; off = n1; }
    float4 v = *(const float4*)(s + (i - off));
    uint2 o;
    o.x = pkbf(v.x, v.y);
    o.y = pkbf(v.z, v.w);
    *(uint2*)(dst + i) = o;
}

// ============================================================
// GEMM1 v5: qkv = x*W_attn^T + b_attn — 8-wave 128x128 tile.
// Single-buffered gld16 staging (32 KB LDS) + __launch_bounds__(512,6):
// 24 waves/CU = THREE 8-wave blocks resident -> 768 = 3x256 zero tail;
// 3 co-resident blocks overlap each other's DMA drains. (R9 win.)
// grid (24, 32): XCD = x%8 — W n-slices L2-resident.
// ============================================================
__global__ __launch_bounds__(512, 6) void gemm_qkv(
    const u16* __restrict__ A, const u16* __restrict__ B, const float* __restrict__ bias,
    u16* __restrict__ Qo, u16* __restrict__ Ko, u16* __restrict__ Vto)
{
    __shared__ __align__(16) u16 SMEM[16384];      // As[128*64] | Bs[128*64]; T aliases
    u16* As = SMEM;
    u16* Bs = SMEM + 8192;
    const int n0 = blockIdx.x * 128, m0 = blockIdx.y * 128;
    const int tid = threadIdx.x;
    const int wave = tid >> 6, lane = tid & 63;
    const int l16 = lane & 15, quad = lane >> 4;
    const int wm = wave >> 2, wn = wave & 3;       // 2x4 wave grid
    const int ldr = lane >> 3;
    const int csw = ((lane & 7) ^ ldr) * 8;        // swizzled k-chunk (elems)

    f32x4 acc[4][2];
#pragma unroll
    for (int i = 0; i < 4; ++i)
#pragma unroll
        for (int j = 0; j < 2; ++j) acc[i][j] = f32x4{0.f, 0.f, 0.f, 0.f};

    const int aorb = wave >> 2;                    // 0: stage A, 1: stage B
    u16* stgbuf = aorb ? Bs : As;
    const u16* stgsrc = aorb ? B : A;
    const int stgbase = aorb ? n0 : m0;

    for (int k0 = 0; k0 < 1024; k0 += 64) {
        __syncthreads();
#pragma unroll
        for (int t = 0; t < 4; ++t) {
            const int c = (wave & 3) * 4 + t;      // 0..15
            const int row = c * 8 + ldr;
            gld16(stgsrc + (size_t)(stgbase + row) * 1024 + k0 + csw,
                  &stgbuf[c * 512 + lane * 8]);
        }
        __syncthreads();
#pragma unroll
        for (int ks = 0; ks < 2; ++ks) {
            bf16x8 af[4], bf[2];
#pragma unroll
            for (int i = 0; i < 4; ++i)
                af[i] = *(const bf16x8*)&As[(wm * 64 + i * 16 + l16) * 64 +
                                            ((ks * 4 + quad) ^ (l16 & 7)) * 8];
#pragma unroll
            for (int j = 0; j < 2; ++j)
                bf[j] = *(const bf16x8*)&Bs[(wn * 32 + j * 16 + l16) * 64 +
                                            ((ks * 4 + quad) ^ (l16 & 7)) * 8];
#pragma unroll
            for (int i = 0; i < 4; ++i)
#pragma unroll
                for (int j = 0; j < 2; ++j)
                    acc[i][j] = MFMA16(af[i], bf[j], acc[i][j]);
        }
    }

    const int part = blockIdx.x >> 3;              // 0=q,1=k,2=v
    const int hbase = (blockIdx.x & 7) << 1;
    if (part != 2) {
        const int h = hbase + (wn >> 1);           // uniform per wave
#pragma unroll
        for (int j = 0; j < 2; ++j) {
            const int f = n0 + wn * 32 + j * 16 + l16;
            const int d = f & 63;
            const float bj = bias[f];
#pragma unroll
            for (int i = 0; i < 4; ++i) {
#pragma unroll
                for (int r = 0; r < 4; ++r) {
                    const int m = m0 + wm * 64 + i * 16 + quad * 4 + r;
                    const int b = m >> 11, s = m & 2047;
                    const float val = acc[i][j][r] + bj;
                    if (part == 0)
                        Qo[(((size_t)(b * HH + h)) * SS + s) * DD + d] = f2bf(val * QSCALE);
                    else
                        Ko[(((size_t)(b * HH + h)) * SS + s) * DD + d] = f2bf(val);
                }
            }
        }
    } else {
        // V: transpose C-tile (128 m x 128 f) through T (aliases SMEM),
        // two m-half passes, coalesced 8B stores to [B,H,D,S].
        u16* T = SMEM;                             // 128 x 72 = 18432 B
#pragma unroll
        for (int wmr = 0; wmr < 2; ++wmr) {
            __syncthreads();
            if (wm == wmr) {
#pragma unroll
                for (int j = 0; j < 2; ++j) {
                    const float bj = bias[n0 + wn * 32 + j * 16 + l16];
#pragma unroll
                    for (int i = 0; i < 4; ++i) {
                        uint2 pw;
                        pw.x = pkbf(acc[i][j][0] + bj, acc[i][j][1] + bj);
                        pw.y = pkbf(acc[i][j][2] + bj, acc[i][j][3] + bj);
                        *(uint2*)&T[(wn * 32 + j * 16 + l16) * 72 + i * 16 + quad * 4] = pw;
                    }
                }
            }
            __syncthreads();
            const int frow = tid >> 2;             // 0..127 (f_local)
            const int qtr = tid & 3;
            const int h = hbase + (frow >> 6);
            const int d = frow & 63;
            const int mg = m0 + wmr * 64;
            const int b = mg >> 11, sbase = mg & 2047;
            u16* dstrow = Vto + (((size_t)(b * HH + h)) * DD + d) * SS + sbase;
#pragma unroll
            for (int l = 0; l < 4; ++l) {
                const int mo = qtr * 16 + l * 4;
                *(uint2*)(dstrow + mo) = *(const uint2*)&T[frow * 72 + mo];
            }
        }
    }
}

// ============================================================
// GEMM2 v5: out = o*W_proj^T + b_proj (fp32) — 64x128 tile, 8 waves,
// double-buffered staging, grid (64, 8) (XCD = m%8: A-rows L2-local,
// W_proj 2.1 MB L2-resident — R6 win). 512 blocks = 2/CU exact.
// ============================================================
__global__ __launch_bounds__(512, 4) void gemm_proj(
    const u16* __restrict__ A, const u16* __restrict__ B, const float* __restrict__ bias,
    float* __restrict__ out)
{
    __shared__ __align__(16) u16 SMEM[2][12288];   // [buf]{As[64*64] | Bs[128*64]}
    const int n0 = blockIdx.y * 128, m0 = blockIdx.x * 64;
    const int tid = threadIdx.x;
    const int wave = tid >> 6, lane = tid & 63;
    const int l16 = lane & 15, quad = lane >> 4;
    const int wm = wave >> 2, wn = wave & 3;       // 2x4 wave grid
    const int ldr = lane >> 3;
    const int csw = ((lane & 7) ^ ldr) * 8;

    f32x4 acc[2][2];
#pragma unroll
    for (int i = 0; i < 2; ++i)
#pragma unroll
        for (int j = 0; j < 2; ++j) acc[i][j] = f32x4{0.f, 0.f, 0.f, 0.f};

    auto stage = [&](int k0, int buf) {
#pragma unroll
        for (int t = 0; t < 3; ++t) {
            const int c = wave * 3 + t;            // 0..23: A chunks 0-7, B 8-23
            if (c < 8) {
                const int row = c * 8 + ldr;
                gld16(A + (size_t)(m0 + row) * 1024 + k0 + csw,
                      &SMEM[buf][c * 512 + lane * 8]);
            } else {
                const int c2 = c - 8;
                const int row = c2 * 8 + ldr;
                gld16(B + (size_t)(n0 + row) * 1024 + k0 + csw,
                      &SMEM[buf][4096 + c2 * 512 + lane * 8]);
            }
        }
    };

    stage(0, 0);                                   // prologue
    for (int k0 = 0; k0 < 1024; k0 += 64) {
        const int cur = (k0 >> 6) & 1;
        __syncthreads();
        if (k0 + 64 < 1024) stage(k0 + 64, cur ^ 1);
        const u16* As = SMEM[cur];
        const u16* Bs = SMEM[cur] + 4096;
#pragma unroll
        for (int ks = 0; ks < 2; ++ks) {
            bf16x8 af[2], bf[2];
#pragma unroll
            for (int i = 0; i < 2; ++i)
                af[i] = *(const bf16x8*)&As[(wm * 32 + i * 16 + l16) * 64 +
                                            ((ks * 4 + quad) ^ (l16 & 7)) * 8];
#pragma unroll
            for (int j = 0; j < 2; ++j)
                bf[j] = *(const bf16x8*)&Bs[(wn * 32 + j * 16 + l16) * 64 +
                                            ((ks * 4 + quad) ^ (l16 & 7)) * 8];
#pragma unroll
            for (int i = 0; i < 2; ++i)
#pragma unroll
                for (int j = 0; j < 2; ++j)
                    acc[i][j] = MFMA16(af[i], bf[j], acc[i][j]);
        }
    }
#pragma unroll
    for (int j = 0; j < 2; ++j) {
        const int f = n0 + wn * 32 + j * 16 + l16;
        const float bj = bias[f];
#pragma unroll
        for (int i = 0; i < 2; ++i) {
#pragma unroll
            for (int r = 0; r < 4; ++r) {
                const int m = m0 + wm * 32 + i * 16 + quad * 4 + r;
                out[(size_t)m * EE + f] = acc[i][j][r] + bj;
            }
        }
    }
}

// ============================================================
// MFMA flash attention v8: best-measured attn (~38 µs).
// Constraint set (R5-R7): >=2 blocks/CU AND balanced per-block work
// AND K/V reuse can't all hold at 256-thr blocks; v8 is the local opt.
// 512 blocks x 256 thr (2/CU), dbuf K/V pairs, two k-tiles per barrier,
// pair-balanced q-tiles (33 phases/block), setprio.
// grid (32,16): x = bh -> XCD = bh % 8 (L2 locality, round 2 win).
// ============================================================
__global__ __launch_bounds__(256, 2) void attn(
    const u16* __restrict__ Q, const u16* __restrict__ K, const u16* __restrict__ VT,
    u16* __restrict__ O)
{
    const int p = blockIdx.y;              // 0..15  (pair index)
    const int bh = blockIdx.x;             // 0..31  -> XCD = bh % 8
    const int tid = threadIdx.x;
    const int wave = tid >> 6, lane = tid & 63;
    const int l16 = lane & 15, quad = lane >> 4;
    const int ldr = lane >> 3;
    const int csw = ((lane & 7) ^ ldr) * 8;
    __shared__ __align__(16) u16 Ks[2][2][64 * 64];   // [buf][sub]
    __shared__ __align__(16) u16 Vts[2][2][64 * 64];
    __shared__ __align__(16) u16 Ps[64 * 72];

    const u16* qptr = Q + (size_t)bh * SS * DD;
    const u16* kptr = K + (size_t)bh * SS * DD;
    const u16* vtptr = VT + (size_t)bh * DD * SS;
    const int b = bh >> 4, h = bh & 15;

    // stage k-tile `t` (and matching V^T columns) into [buf][sub]
    auto stage = [&](int t, int buf, int sub) {
#pragma unroll
        for (int c = 0; c < 2; ++c) {
            const int a0 = wave * 2 + c;
            const int row = a0 * 8 + ldr;
            gld16(kptr + (size_t)(t * 64 + row) * DD + csw,
                  &Ks[buf][sub][a0 * 512 + lane * 8]);
            gld16(vtptr + (size_t)row * SS + t * 64 + csw,
                  &Vts[buf][sub][a0 * 512 + lane * 8]);
        }
    };

    for (int half = 0; half < 2; ++half) {
        const int qb = half ? p : 31 - p;          // long tile first
        const int qrow = qb * 64 + wave * 16 + l16;   // this lane's query
        bf16x8 bq[2];
#pragma unroll
        for (int ks = 0; ks < 2; ++ks)
            bq[ks] = *(const bf16x8*)(qptr + (size_t)qrow * DD + ks * 32 + quad * 8);

        float lp = 0.f;                    // per-lane partial l
        f32x4 o_acc[4];
#pragma unroll
        for (int j = 0; j < 4; ++j) o_acc[j] = f32x4{0.f, 0.f, 0.f, 0.f};

        // per-subtile compute: QK^T -> masked exp2 -> P -> O += V^T P^T
        auto tile_compute = [&](const u16* Kb, const u16* Vb, int t) {
            f32x4 s[4];
#pragma unroll
            for (int j = 0; j < 4; ++j) s[j] = f32x4{0.f, 0.f, 0.f, 0.f};
            __builtin_amdgcn_s_setprio(1);
#pragma unroll
            for (int ks = 0; ks < 2; ++ks) {
#pragma unroll
                for (int j = 0; j < 4; ++j) {
                    bf16x8 ak = *(const bf16x8*)&Kb[(j * 16 + l16) * 64 +
                                                    ((ks * 4 + quad) ^ (l16 & 7)) * 8];
                    s[j] = MFMA16(ak, bq[ks], s[j]);
                }
            }
            __builtin_amdgcn_s_setprio(0);
            if (t == qb) {                 // mask only on the diagonal tile
#pragma unroll
                for (int j = 0; j < 4; ++j)
#pragma unroll
                    for (int r = 0; r < 4; ++r) {
                        const int key = t * 64 + j * 16 + quad * 4 + r;
                        if (key > qrow) s[j][r] = -INFINITY;   // exp2 -> 0
                    }
            }
#pragma unroll
            for (int j = 0; j < 4; ++j) {
                const float p0 = __builtin_amdgcn_exp2f(s[j][0]);
                const float p1 = __builtin_amdgcn_exp2f(s[j][1]);
                const float p2 = __builtin_amdgcn_exp2f(s[j][2]);
                const float p3 = __builtin_amdgcn_exp2f(s[j][3]);
                lp += (p0 + p1) + (p2 + p3);
                uint2 pw; pw.x = pkbf(p0, p1); pw.y = pkbf(p2, p3);
                *(uint2*)&Ps[(wave * 16 + l16) * 72 + j * 16 + quad * 4] = pw;
            }
            // O^T += V^T·P^T (Ps wave-private: lgkm ordering suffices)
            __builtin_amdgcn_s_setprio(1);
#pragma unroll
            for (int ks = 0; ks < 2; ++ks) {
                bf16x8 bp = *(const bf16x8*)&Ps[(wave * 16 + l16) * 72 + ks * 32 + quad * 8];
#pragma unroll
                for (int j = 0; j < 4; ++j) {
                    bf16x8 av = *(const bf16x8*)&Vb[(j * 16 + l16) * 64 +
                                                    ((ks * 4 + quad) ^ (l16 & 7)) * 8];
                    o_acc[j] = MFMA16(av, bp, o_acc[j]);
                }
            }
            __builtin_amdgcn_s_setprio(0);
        };

        // protect buf0 from the previous half's in-flight readers
        __syncthreads();
        // prologue: stage tile pair {0, min(1,qb)} into buf 0
        stage(0, 0, 0);
        stage(qb < 1 ? qb : 1, 0, 1);

        for (int kb = 0; kb <= qb; kb += 2) {
            const int cur = (kb >> 1) & 1;
            // vmcnt(0)+barrier (compiler-emitted): buf[cur] pair ready,
            // buf[cur^1] has no readers left.
            __syncthreads();
            if (kb + 2 <= qb) {            // prefetch next pair into buf^1
                stage(kb + 2, cur ^ 1, 0);
                const int t3 = kb + 3 > qb ? qb : kb + 3;   // clamp (no OOB)
                stage(t3, cur ^ 1, 1);
            }
            tile_compute(Ks[cur][0], Vts[cur][0], kb);
            if (kb + 1 <= qb)
                tile_compute(Ks[cur][1], Vts[cur][1], kb + 1);
        }

        // epilogue: quad-reduce l once, normalize, store (lane owns query qrow)
        float l = lp;
        l += __shfl_xor(l, 16);
        l += __shfl_xor(l, 32);
        const float inv = 1.0f / l;
#pragma unroll
        for (int j = 0; j < 4; ++j) {
            uint2 o4;
            o4.x = pkbf(o_acc[j][0] * inv, o_acc[j][1] * inv);
            o4.y = pkbf(o_acc[j][2] * inv, o_acc[j][3] * inv);
            *(uint2*)&O[((size_t)(b * SS + qrow)) * EE + h * DD + j * 16 + quad * 4] = o4;
        }
    }
}

extern "C" void kernel_launch(void* const* d_in, const int* in_sizes, int n_in,
                              void* d_out, int out_size, void* d_ws, size_t ws_size,
                              hipStream_t stream) {
    const float* x      = (const float*)d_in[0];  // [B,S,E] fp32
    const float* W_attn = (const float*)d_in[1];  // [3E,E] fp32
    const float* b_attn = (const float*)d_in[2];  // [3E] fp32
    const float* W_proj = (const float*)d_in[3];  // [E,E] fp32
    const float* b_proj = (const float*)d_in[4];  // [E] fp32
    float* out = (float*)d_out;                   // fp32 [B,S,E]

    // ws layout (u16 elems): xb 4.19M | wab 3.15M | wpb 1.05M | q 4.19M | k 4.19M | vt 4.19M
    u16* xb  = (u16*)d_ws;
    u16* wab = xb + (size_t)4096 * 1024;
    u16* wpb = wab + (size_t)3072 * 1024;
    u16* qw  = wpb + (size_t)1024 * 1024;
    u16* kw  = qw + (size_t)BB * HH * SS * DD;
    u16* vtw = kw + (size_t)BB * HH * SS * DD;
    u16* ow  = xb;                                 // xb dead after gemm_qkv

    convert_all<<<8192, 256, 0, stream>>>(x, W_attn, W_proj, xb);
    gemm_qkv<<<dim3(24, 32), 512, 0, stream>>>(xb, wab, b_attn, qw, kw, vtw);
    attn<<<dim3(32, 16), 256, 0, stream>>>(qw, kw, vtw, ow);
    gemm_proj<<<dim3(64, 8), 512, 0, stream>>>(ow, wpb, b_proj, out);
}

// Round 12
// 172.166 us; speedup vs baseline: 1.2011x; 1.0320x over previous
//
#include <hip/hip_runtime.h>
#include <hip/hip_bf16.h>

typedef unsigned short u16;
typedef unsigned int u32;
typedef float f32x4 __attribute__((ext_vector_type(4)));
typedef short bf16x8 __attribute__((ext_vector_type(8)));

// ---- constants (B=2, S=2048, E=1024, H=16, D=64) ----
#define BB 2
#define SS 2048
#define EE 1024
#define HH 16
#define DD 64
// q pre-scale: 1/sqrt(D) * log2(e) — scores land directly in exp2 domain.
#define QSCALE 0.18033688011f

__device__ __forceinline__ u16 f2bf(float f) {
    union { u32 i; float f; } x; x.f = f;
    return (u16)((x.i + 0x7FFFu + ((x.i >> 16) & 1u)) >> 16);
}
__device__ __forceinline__ u32 pkbf(float a, float b) {
    __hip_bfloat162 h = __float22bfloat162_rn(make_float2(a, b));
    union { __hip_bfloat162 h; u32 u; } c; c.h = h; return c.u;
}

#define MFMA16(a, b, c) __builtin_amdgcn_mfma_f32_16x16x32_bf16((a), (b), (c), 0, 0, 0)

// async global->LDS DMA, 16B per lane; LDS dest = wave-uniform base + lane*16
__device__ __forceinline__ void gld16(const u16* g, u16* l) {
    __builtin_amdgcn_global_load_lds(
        (const __attribute__((address_space(1))) void*)g,
        (__attribute__((address_space(3))) void*)l,
        16, 0, 0);
}

// ============================================================
// fused fp32 -> bf16 convert of x | W_attn | W_proj into contiguous ws.
// R10 lesson: this dispatch is LOAD-BEARING — it deduplicates the fp32
// read and keeps GEMM staging on the async gld16 path.
// ============================================================
__global__ __launch_bounds__(256) void convert_all(
    const float* __restrict__ x, const float* __restrict__ wa,
    const float* __restrict__ wp, u16* __restrict__ dst)
{
    const size_t n0 = (size_t)4096 * 1024;
    const size_t n1 = n0 + (size_t)3072 * 1024;
    size_t i = ((size_t)blockIdx.x * 256 + threadIdx.x) * 4;
    const float* s;
    size_t off;
    if (i < n0)      { s = x;  off = 0;  }
    else if (i < n1) { s = wa; off = n0; }
    else             { s = wp; off = n1; }
    float4 v = *(const float4*)(s + (i - off));
    uint2 o;
    o.x = pkbf(v.x, v.y);
    o.y = pkbf(v.z, v.w);
    *(uint2*)(dst + i) = o;
}

// ============================================================
// GEMM1 v5: qkv = x*W_attn^T + b_attn — 8-wave 128x128 tile.
// Single-buffered gld16 staging (32 KB LDS) + __launch_bounds__(512,6):
// 3 blocks/CU -> 768 = 3x256 zero tail. (R9 win.)
// grid (24, 32): XCD = x%8 — W n-slices L2-resident.
// ============================================================
__global__ __launch_bounds__(512, 6) void gemm_qkv(
    const u16* __restrict__ A, const u16* __restrict__ B, const float* __restrict__ bias,
    u16* __restrict__ Qo, u16* __restrict__ Ko, u16* __restrict__ Vto)
{
    __shared__ __align__(16) u16 SMEM[16384];      // As[128*64] | Bs[128*64]; T aliases
    u16* As = SMEM;
    u16* Bs = SMEM + 8192;
    const int n0 = blockIdx.x * 128, m0 = blockIdx.y * 128;
    const int tid = threadIdx.x;
    const int wave = tid >> 6, lane = tid & 63;
    const int l16 = lane & 15, quad = lane >> 4;
    const int wm = wave >> 2, wn = wave & 3;       // 2x4 wave grid
    const int ldr = lane >> 3;
    const int csw = ((lane & 7) ^ ldr) * 8;        // swizzled k-chunk (elems)

    f32x4 acc[4][2];
#pragma unroll
    for (int i = 0; i < 4; ++i)
#pragma unroll
        for (int j = 0; j < 2; ++j) acc[i][j] = f32x4{0.f, 0.f, 0.f, 0.f};

    const int aorb = wave >> 2;                    // 0: stage A, 1: stage B
    u16* stgbuf = aorb ? Bs : As;
    const u16* stgsrc = aorb ? B : A;
    const int stgbase = aorb ? n0 : m0;

    for (int k0 = 0; k0 < 1024; k0 += 64) {
        __syncthreads();
#pragma unroll
        for (int t = 0; t < 4; ++t) {
            const int c = (wave & 3) * 4 + t;      // 0..15
            const int row = c * 8 + ldr;
            gld16(stgsrc + (size_t)(stgbase + row) * 1024 + k0 + csw,
                  &stgbuf[c * 512 + lane * 8]);
        }
        __syncthreads();
#pragma unroll
        for (int ks = 0; ks < 2; ++ks) {
            bf16x8 af[4], bf[2];
#pragma unroll
            for (int i = 0; i < 4; ++i)
                af[i] = *(const bf16x8*)&As[(wm * 64 + i * 16 + l16) * 64 +
                                            ((ks * 4 + quad) ^ (l16 & 7)) * 8];
#pragma unroll
            for (int j = 0; j < 2; ++j)
                bf[j] = *(const bf16x8*)&Bs[(wn * 32 + j * 16 + l16) * 64 +
                                            ((ks * 4 + quad) ^ (l16 & 7)) * 8];
#pragma unroll
            for (int i = 0; i < 4; ++i)
#pragma unroll
                for (int j = 0; j < 2; ++j)
                    acc[i][j] = MFMA16(af[i], bf[j], acc[i][j]);
        }
    }

    const int part = blockIdx.x >> 3;              // 0=q,1=k,2=v
    const int hbase = (blockIdx.x & 7) << 1;
    if (part != 2) {
        const int h = hbase + (wn >> 1);           // uniform per wave
#pragma unroll
        for (int j = 0; j < 2; ++j) {
            const int f = n0 + wn * 32 + j * 16 + l16;
            const int d = f & 63;
            const float bj = bias[f];
#pragma unroll
            for (int i = 0; i < 4; ++i) {
#pragma unroll
                for (int r = 0; r < 4; ++r) {
                    const int m = m0 + wm * 64 + i * 16 + quad * 4 + r;
                    const int b = m >> 11, s = m & 2047;
                    const float val = acc[i][j][r] + bj;
                    if (part == 0)
                        Qo[(((size_t)(b * HH + h)) * SS + s) * DD + d] = f2bf(val * QSCALE);
                    else
                        Ko[(((size_t)(b * HH + h)) * SS + s) * DD + d] = f2bf(val);
                }
            }
        }
    } else {
        // V: transpose C-tile (128 m x 128 f) through T (aliases SMEM),
        // two m-half passes, coalesced 8B stores to [B,H,D,S].
        u16* T = SMEM;                             // 128 x 72 = 18432 B
#pragma unroll
        for (int wmr = 0; wmr < 2; ++wmr) {
            __syncthreads();
            if (wm == wmr) {
#pragma unroll
                for (int j = 0; j < 2; ++j) {
                    const float bj = bias[n0 + wn * 32 + j * 16 + l16];
#pragma unroll
                    for (int i = 0; i < 4; ++i) {
                        uint2 pw;
                        pw.x = pkbf(acc[i][j][0] + bj, acc[i][j][1] + bj);
                        pw.y = pkbf(acc[i][j][2] + bj, acc[i][j][3] + bj);
                        *(uint2*)&T[(wn * 32 + j * 16 + l16) * 72 + i * 16 + quad * 4] = pw;
                    }
                }
            }
            __syncthreads();
            const int frow = tid >> 2;             // 0..127 (f_local)
            const int qtr = tid & 3;
            const int h = hbase + (frow >> 6);
            const int d = frow & 63;
            const int mg = m0 + wmr * 64;
            const int b = mg >> 11, sbase = mg & 2047;
            u16* dstrow = Vto + (((size_t)(b * HH + h)) * DD + d) * SS + sbase;
#pragma unroll
            for (int l = 0; l < 4; ++l) {
                const int mo = qtr * 16 + l * 4;
                *(uint2*)(dstrow + mo) = *(const uint2*)&T[frow * 72 + mo];
            }
        }
    }
}

// ============================================================
// GEMM2 v5: out = o*W_proj^T + b_proj (fp32) — 64x128 tile, 8 waves,
// double-buffered staging, grid (64, 8) (XCD = m%8, R6 win).
// ============================================================
__global__ __launch_bounds__(512, 4) void gemm_proj(
    const u16* __restrict__ A, const u16* __restrict__ B, const float* __restrict__ bias,
    float* __restrict__ out)
{
    __shared__ __align__(16) u16 SMEM[2][12288];   // [buf]{As[64*64] | Bs[128*64]}
    const int n0 = blockIdx.y * 128, m0 = blockIdx.x * 64;
    const int tid = threadIdx.x;
    const int wave = tid >> 6, lane = tid & 63;
    const int l16 = lane & 15, quad = lane >> 4;
    const int wm = wave >> 2, wn = wave & 3;       // 2x4 wave grid
    const int ldr = lane >> 3;
    const int csw = ((lane & 7) ^ ldr) * 8;

    f32x4 acc[2][2];
#pragma unroll
    for (int i = 0; i < 2; ++i)
#pragma unroll
        for (int j = 0; j < 2; ++j) acc[i][j] = f32x4{0.f, 0.f, 0.f, 0.f};

    auto stage = [&](int k0, int buf) {
#pragma unroll
        for (int t = 0; t < 3; ++t) {
            const int c = wave * 3 + t;            // 0..23: A chunks 0-7, B 8-23
            if (c < 8) {
                const int row = c * 8 + ldr;
                gld16(A + (size_t)(m0 + row) * 1024 + k0 + csw,
                      &SMEM[buf][c * 512 + lane * 8]);
            } else {
                const int c2 = c - 8;
                const int row = c2 * 8 + ldr;
                gld16(B + (size_t)(n0 + row) * 1024 + k0 + csw,
                      &SMEM[buf][4096 + c2 * 512 + lane * 8]);
            }
        }
    };

    stage(0, 0);                                   // prologue
    for (int k0 = 0; k0 < 1024; k0 += 64) {
        const int cur = (k0 >> 6) & 1;
        __syncthreads();
        if (k0 + 64 < 1024) stage(k0 + 64, cur ^ 1);
        const u16* As = SMEM[cur];
        const u16* Bs = SMEM[cur] + 4096;
#pragma unroll
        for (int ks = 0; ks < 2; ++ks) {
            bf16x8 af[2], bf[2];
#pragma unroll
            for (int i = 0; i < 2; ++i)
                af[i] = *(const bf16x8*)&As[(wm * 32 + i * 16 + l16) * 64 +
                                            ((ks * 4 + quad) ^ (l16 & 7)) * 8];
#pragma unroll
            for (int j = 0; j < 2; ++j)
                bf[j] = *(const bf16x8*)&Bs[(wn * 32 + j * 16 + l16) * 64 +
                                            ((ks * 4 + quad) ^ (l16 & 7)) * 8];
#pragma unroll
            for (int i = 0; i < 2; ++i)
#pragma unroll
                for (int j = 0; j < 2; ++j)
                    acc[i][j] = MFMA16(af[i], bf[j], acc[i][j]);
        }
    }
#pragma unroll
    for (int j = 0; j < 2; ++j) {
        const int f = n0 + wn * 32 + j * 16 + l16;
        const float bj = bias[f];
#pragma unroll
        for (int i = 0; i < 2; ++i) {
#pragma unroll
            for (int r = 0; r < 4; ++r) {
                const int m = m0 + wm * 32 + i * 16 + quad * 4 + r;
                out[(size_t)m * EE + f] = acc[i][j][r] + bj;
            }
        }
    }
}

// ============================================================
// MFMA flash attention v11 "k-split waves": v8's outer structure
// (grid (32,16), 256 thr, pair-balanced halves, 2 blocks/CU, dbuf,
// 2 tiles/barrier) but each wave computes ALL 64 q-rows (Q in regs,
// 4 nsub x 2 ks bf16x8) against only ITS 16 keys per tile (rows
// wave*16..+15). Swapped-QK^T C layout (key=quad*4+r, q=l16) IS the
// PV B-operand layout when the two subtiles' key groups interleave
// into one K=32 k-space {sub0:quad*4+r | sub1:quad*4+r} = quad*8+e —
// P never touches LDS (Ps deleted). LDS reads/wave/tile: ak 8->2 b128,
// av 8 b128 -> 4x2 b64. Per-CU LDS per phase-pair ~3800 -> ~900 cy
// (R6 diagnosis: attn is LDS-read-bound). Cross-wave O/l reduction
// once per half through the then-dead K/V LDS (chunk-XOR-swizzled).
// MFMA count, staging traffic, exp2 count: all unchanged vs v8.
// ============================================================
__global__ __launch_bounds__(256, 2) void attn(
    const u16* __restrict__ Q, const u16* __restrict__ K, const u16* __restrict__ VT,
    u16* __restrict__ O)
{
    const int p = blockIdx.y;              // 0..15  (pair index)
    const int bh = blockIdx.x;             // 0..31  -> XCD = bh % 8
    const int tid = threadIdx.x;
    const int wave = tid >> 6, lane = tid & 63;
    const int l16 = lane & 15, quad = lane >> 4;
    const int ldr = lane >> 3;
    const int csw = ((lane & 7) ^ ldr) * 8;
    // one contiguous 64 KB region: Ks[2][2][4096] | Vts[2][2][4096];
    // Ored ([4 waves][64 q][64 d] f32, chunk-swizzled) overlays at half-end.
    __shared__ __align__(16) u16 SMEM[32768];
    __shared__ float Lred[4][64];
    u16* const Ksb = SMEM;
    u16* const Vtb = SMEM + 16384;

    const u16* qptr = Q + (size_t)bh * SS * DD;
    const u16* kptr = K + (size_t)bh * SS * DD;
    const u16* vtptr = VT + (size_t)bh * DD * SS;
    const int b = bh >> 4, h = bh & 15;

    // stage k-tile `t` (K rows + V^T cols) into [buf][sub]
    auto stage = [&](int t, int buf, int sub) {
#pragma unroll
        for (int c = 0; c < 2; ++c) {
            const int a0 = wave * 2 + c;
            const int row = a0 * 8 + ldr;
            gld16(kptr + (size_t)(t * 64 + row) * DD + csw,
                  Ksb + (buf * 2 + sub) * 4096 + a0 * 512 + lane * 8);
            gld16(vtptr + (size_t)row * SS + t * 64 + csw,
                  Vtb + (buf * 2 + sub) * 4096 + a0 * 512 + lane * 8);
        }
    };

    for (int half = 0; half < 2; ++half) {
        const int qb = half ? p : 31 - p;          // long tile first

        // Q in regs: q = qb*64 + n*16 + l16 (lane = B-operand n), d = ks*32 + quad*8
        bf16x8 bq[4][2];
#pragma unroll
        for (int n = 0; n < 4; ++n)
#pragma unroll
            for (int ks = 0; ks < 2; ++ks)
                bq[n][ks] = *(const bf16x8*)(qptr +
                    (size_t)(qb * 64 + n * 16 + l16) * DD + ks * 32 + quad * 8);

        float lp[4] = {0.f, 0.f, 0.f, 0.f};       // per-q-sub partial l (this wave's keys)
        f32x4 o_acc[4][4];                         // [dsub][nsub]
#pragma unroll
        for (int d = 0; d < 4; ++d)
#pragma unroll
            for (int n = 0; n < 4; ++n) o_acc[d][n] = f32x4{0.f, 0.f, 0.f, 0.f};

        // previous half fully done with SMEM (Ored reads) before restaging
        __syncthreads();
        stage(0, 0, 0);
        stage(qb < 1 ? qb : 1, 0, 1);

        for (int kb = 0; kb <= qb; kb += 2) {
            const int cur = (kb >> 1) & 1;
            // compiler-emitted vmcnt(0)+barrier: buf[cur] pair ready, buf^1 free
            __syncthreads();
            if (kb + 2 <= qb) {
                stage(kb + 2, cur ^ 1, 0);
                stage(kb + 3 > qb ? qb : kb + 3, cur ^ 1, 1);
            }

            u32 pk[2][4][2];                       // [sub][nsub]{lo,hi}
#pragma unroll
            for (int sub = 0; sub < 2; ++sub) {
                const int t = kb + sub;
                f32x4 s[4];
                if (t <= qb) {
#pragma unroll
                    for (int n = 0; n < 4; ++n) s[n] = f32x4{0.f, 0.f, 0.f, 0.f};
                    const u16* Kc = Ksb + (cur * 2 + sub) * 4096;
                    __builtin_amdgcn_s_setprio(1);
#pragma unroll
                    for (int ks = 0; ks < 2; ++ks) {
                        // A = K rows: m=l16 -> key wave*16+l16, k = d quad*8+e
                        bf16x8 ak = *(const bf16x8*)&Kc[(wave * 16 + l16) * 64 +
                                        ((ks * 4 + quad) ^ (l16 & 7)) * 8];
#pragma unroll
                        for (int n = 0; n < 4; ++n)
                            s[n] = MFMA16(ak, bq[n][ks], s[n]);
                    }
                    __builtin_amdgcn_s_setprio(0);
                    if (t == qb) {                 // diagonal tile mask
#pragma unroll
                        for (int n = 0; n < 4; ++n)
#pragma unroll
                            for (int r = 0; r < 4; ++r) {
                                const int key = t * 64 + wave * 16 + quad * 4 + r;
                                const int qq  = qb * 64 + n * 16 + l16;
                                if (key > qq) s[n][r] = -INFINITY;
                            }
                    }
                } else {                           // dead sub (odd tail) -> p = 0
#pragma unroll
                    for (int n = 0; n < 4; ++n)
                        s[n] = f32x4{-INFINITY, -INFINITY, -INFINITY, -INFINITY};
                }
#pragma unroll
                for (int n = 0; n < 4; ++n) {
                    const float p0 = __builtin_amdgcn_exp2f(s[n][0]);
                    const float p1 = __builtin_amdgcn_exp2f(s[n][1]);
                    const float p2 = __builtin_amdgcn_exp2f(s[n][2]);
                    const float p3 = __builtin_amdgcn_exp2f(s[n][3]);
                    lp[n] += (p0 + p1) + (p2 + p3);
                    pk[sub][n][0] = pkbf(p0, p1);
                    pk[sub][n][1] = pkbf(p2, p3);
                }
            }

            // B = P: lane n=l16=q, k-space = {sub0 keys | sub1 keys} = quad*8+e
            bf16x8 bp[4];
#pragma unroll
            for (int n = 0; n < 4; ++n) {
                union { u32 w[4]; bf16x8 v; } u;
                u.w[0] = pk[0][n][0]; u.w[1] = pk[0][n][1];
                u.w[2] = pk[1][n][0]; u.w[3] = pk[1][n][1];
                bp[n] = u.v;
            }
            // A = V^T: m=l16 -> d dsub*16+l16; k e0-3 from sub0, e4-7 from sub1
            const int vsw = ((wave * 2 + (quad >> 1)) ^ (l16 & 7)) * 8 + (quad & 1) * 4;
            __builtin_amdgcn_s_setprio(1);
#pragma unroll
            for (int d = 0; d < 4; ++d) {
                union { uint2 u2[2]; bf16x8 v; } a;
                a.u2[0] = *(const uint2*)&Vtb[(cur * 2 + 0) * 4096 + (d * 16 + l16) * 64 + vsw];
                a.u2[1] = *(const uint2*)&Vtb[(cur * 2 + 1) * 4096 + (d * 16 + l16) * 64 + vsw];
#pragma unroll
                for (int n = 0; n < 4; ++n)
                    o_acc[d][n] = MFMA16(a.v, bp[n], o_acc[d][n]);
            }
            __builtin_amdgcn_s_setprio(0);
        }

        // ---- cross-wave reduction of l and O through the dead K/V LDS ----
#pragma unroll
        for (int n = 0; n < 4; ++n) {              // reduce over this wave's quads
            lp[n] += __shfl_xor(lp[n], 16);
            lp[n] += __shfl_xor(lp[n], 32);
        }
        __syncthreads();                           // all K/V reads done; SMEM reusable
        if (quad == 0) {
#pragma unroll
            for (int n = 0; n < 4; ++n) Lred[wave][n * 16 + l16] = lp[n];
        }
        float* Ored = (float*)SMEM;                // [wave][q][64], chunk ^ (q&7)
#pragma unroll
        for (int d = 0; d < 4; ++d)
#pragma unroll
            for (int n = 0; n < 4; ++n) {
                const int chunk = (d * 4 + quad) ^ (l16 & 7);
                *(f32x4*)&Ored[wave * 4096 + (n * 16 + l16) * 64 + chunk * 4] = o_acc[d][n];
            }
        __syncthreads();
        {
            const int q = wave * 16 + (lane >> 2); // each wave finalizes 16 q-rows
            const int dg = lane & 3;               // 16-d group
            const float l = Lred[0][q] + Lred[1][q] + Lred[2][q] + Lred[3][q];
            const float inv = 1.0f / l;
            u32 wout[8];
#pragma unroll
            for (int dv = 0; dv < 4; ++dv) {
                const int chunk = (dg * 4 + dv) ^ (q & 7);
                f32x4 acc = f32x4{0.f, 0.f, 0.f, 0.f};
#pragma unroll
                for (int w = 0; w < 4; ++w)
                    acc += *(const f32x4*)&Ored[w * 4096 + q * 64 + chunk * 4];
                wout[dv * 2 + 0] = pkbf(acc[0] * inv, acc[1] * inv);
                wout[dv * 2 + 1] = pkbf(acc[2] * inv, acc[3] * inv);
            }
            u16* dst = O + ((size_t)(b * SS + qb * 64 + q)) * EE + h * DD + dg * 16;
            *(uint4*)dst = *(const uint4*)&wout[0];
            *(uint4*)(dst + 8) = *(const uint4*)&wout[4];
        }
    }
}

extern "C" void kernel_launch(void* const* d_in, const int* in_sizes, int n_in,
                              void* d_out, int out_size, void* d_ws, size_t ws_size,
                              hipStream_t stream) {
    const float* x      = (const float*)d_in[0];  // [B,S,E] fp32
    const float* W_attn = (const float*)d_in[1];  // [3E,E] fp32
    const float* b_attn = (const float*)d_in[2];  // [3E] fp32
    const float* W_proj = (const float*)d_in[3];  // [E,E] fp32
    const float* b_proj = (const float*)d_in[4];  // [E] fp32
    float* out = (float*)d_out;                   // fp32 [B,S,E]

    // ws layout (u16 elems): xb 4.19M | wab 3.15M | wpb 1.05M | q 4.19M | k 4.19M | vt 4.19M
    u16* xb  = (u16*)d_ws;
    u16* wab = xb + (size_t)4096 * 1024;
    u16* wpb = wab + (size_t)3072 * 1024;
    u16* qw  = wpb + (size_t)1024 * 1024;
    u16* kw  = qw + (size_t)BB * HH * SS * DD;
    u16* vtw = kw + (size_t)BB * HH * SS * DD;
    u16* ow  = xb;                                 // xb dead after gemm_qkv

    convert_all<<<8192, 256, 0, stream>>>(x, W_attn, W_proj, xb);
    gemm_qkv<<<dim3(24, 32), 512, 0, stream>>>(xb, wab, b_attn, qw, kw, vtw);
    attn<<<dim3(32, 16), 256, 0, stream>>>(qw, kw, vtw, ow);
    gemm_proj<<<dim3(64, 8), 512, 0, stream>>>(ow, wpb, b_proj, out);
}